// Round 1
// baseline (1360.054 us; speedup 1.0000x reference)
//
#include <hip/hip_runtime.h>
#include <hip/hip_bf16.h>
#include <stdint.h>

// Problem constants (B=4,S=2048 -> T=8192)
#define T_TOK 8192
#define H_DIM 1024
#define F_DIM 3584
#define E_NUM 8

// GEMM tiling
#define BM 128
#define BN 128
#define BK 32
#define LDT 40   // padded LDS row length in bf16 elems (32 + 8): 80B stride -> 2-way bank alias (free)

typedef __attribute__((ext_vector_type(8))) short bf16x8;
typedef __attribute__((ext_vector_type(4))) float f32x4;

__device__ __forceinline__ short f2bf(float f) {
    union { float f; uint32_t u; } v; v.f = f;
    uint32_t r = v.u + 0x7fffu + ((v.u >> 16) & 1u);   // RNE bf16
    return (short)(r >> 16);
}

// Convert 16 contiguous fp32 -> 16 bf16, store to LDS as two b128 writes.
__device__ __forceinline__ void cvt16_store(const float* __restrict__ src, short* dst) {
    const f32x4* p = (const f32x4*)src;
    f32x4 v0 = p[0], v1 = p[1], v2 = p[2], v3 = p[3];
    bf16x8 s0, s1;
    s0[0]=f2bf(v0[0]); s0[1]=f2bf(v0[1]); s0[2]=f2bf(v0[2]); s0[3]=f2bf(v0[3]);
    s0[4]=f2bf(v1[0]); s0[5]=f2bf(v1[1]); s0[6]=f2bf(v1[2]); s0[7]=f2bf(v1[3]);
    s1[0]=f2bf(v2[0]); s1[1]=f2bf(v2[1]); s1[2]=f2bf(v2[2]); s1[3]=f2bf(v2[3]);
    s1[4]=f2bf(v3[0]); s1[5]=f2bf(v3[1]); s1[6]=f2bf(v3[2]); s1[7]=f2bf(v3[3]);
    *(bf16x8*)dst = s0;
    *((bf16x8*)dst + 1) = s1;
}

__device__ __forceinline__ void zero16_store(short* dst) {
    bf16x8 z;
    #pragma unroll
    for (int i = 0; i < 8; i++) z[i] = 0;
    *(bf16x8*)dst = z;
    *((bf16x8*)dst + 1) = z;
}

// ---------------------------------------------------------------------------
// Router: one wave per token. fp32 logits (exact), top-2, normalized weights,
// append assignment id a=2t+k to per-expert list.
// ---------------------------------------------------------------------------
__global__ void router_kernel(const float* __restrict__ x,
                              const float* __restrict__ gate_w,
                              float* __restrict__ logits_out,
                              int* __restrict__ counts,
                              int* __restrict__ lists,
                              float* __restrict__ wgt) {
    int wave = (blockIdx.x * blockDim.x + threadIdx.x) >> 6;
    int lane = threadIdx.x & 63;
    if (wave >= T_TOK) return;
    const float* xr = x + (size_t)wave * H_DIM;

    float acc[E_NUM];
    #pragma unroll
    for (int e = 0; e < E_NUM; e++) acc[e] = 0.f;

    for (int i = lane; i < H_DIM; i += 64) {
        float xv = xr[i];
        #pragma unroll
        for (int e = 0; e < E_NUM; e++) acc[e] += xv * gate_w[e * H_DIM + i];
    }
    #pragma unroll
    for (int off = 32; off > 0; off >>= 1) {
        #pragma unroll
        for (int e = 0; e < E_NUM; e++) acc[e] += __shfl_xor(acc[e], off);
    }

    if (lane == 0) {
        int t = wave;
        #pragma unroll
        for (int e = 0; e < E_NUM; e++) logits_out[t * E_NUM + e] = acc[e];
        // top-2 (strict > keeps lowest index on ties, matching lax.top_k)
        int i0 = 0; float v0 = acc[0];
        #pragma unroll
        for (int e = 1; e < E_NUM; e++) if (acc[e] > v0) { v0 = acc[e]; i0 = e; }
        int i1 = -1; float v1 = -1e30f;
        #pragma unroll
        for (int e = 0; e < E_NUM; e++) if (e != i0 && acc[e] > v1) { v1 = acc[e]; i1 = e; }
        // normalized top-2 softmax weights (common denominator cancels)
        float e1 = __expf(v1 - v0);
        float inv = 1.f / (1.f + e1);
        int a0 = 2 * t, a1 = 2 * t + 1;
        wgt[a0] = inv;
        wgt[a1] = e1 * inv;
        int p0 = atomicAdd(&counts[i0], 1);
        lists[i0 * T_TOK + p0] = a0;
        int p1 = atomicAdd(&counts[i1], 1);
        lists[i1 * T_TOK + p1] = a1;
    }
}

// ---------------------------------------------------------------------------
// GEMM1: per expert e, for its token rows: hgate = silu(x @ w1[e]^T) * (x @ w3[e]^T)
// A = gathered x rows (fp32 -> bf16), B = w1/w3 rows [F,H] (fp32 -> bf16).
// Stores hgate rows (bf16) indexed by assignment id.
// ---------------------------------------------------------------------------
__global__ __launch_bounds__(256, 2)
void gemm1_kernel(const float* __restrict__ x,
                  const float* __restrict__ w1,
                  const float* __restrict__ w3,
                  const int* __restrict__ counts,
                  const int* __restrict__ lists,
                  unsigned short* __restrict__ hgate) {
    const int e = blockIdx.z;
    const int count = counts[e];
    const int mbase = blockIdx.y * BM;
    if (mbase >= count) return;
    const int nbase = blockIdx.x * BN;

    __shared__ short As[BM * LDT];
    __shared__ short B1s[BN * LDT];
    __shared__ short B3s[BN * LDT];

    const int tid = threadIdx.x;
    const int r = tid >> 1;      // 0..127: staging row
    const int half = tid & 1;    // 16-elem half of the 32-wide K slice

    const float* arow = nullptr;
    {
        int m = mbase + r;
        if (m < count) {
            int a = lists[e * T_TOK + m];
            arow = x + (size_t)(a >> 1) * H_DIM;
        }
    }
    const float* b1row = w1 + ((size_t)e * F_DIM + (nbase + r)) * H_DIM;
    const float* b3row = w3 + ((size_t)e * F_DIM + (nbase + r)) * H_DIM;

    const int lane = tid & 63;
    const int wid = tid >> 6;
    const int wm = wid >> 1, wn = wid & 1;
    const int lr = lane & 15, lq = lane >> 4;

    f32x4 acc1[4][4], acc3[4][4];
    #pragma unroll
    for (int i = 0; i < 4; i++)
        #pragma unroll
        for (int j = 0; j < 4; j++) {
            acc1[i][j] = (f32x4){0.f, 0.f, 0.f, 0.f};
            acc3[i][j] = (f32x4){0.f, 0.f, 0.f, 0.f};
        }

    for (int k0 = 0; k0 < H_DIM; k0 += BK) {
        const int koff = k0 + half * 16;
        short* adst = &As[r * LDT + half * 16];
        if (arow) cvt16_store(arow + koff, adst); else zero16_store(adst);
        cvt16_store(b1row + koff, &B1s[r * LDT + half * 16]);
        cvt16_store(b3row + koff, &B3s[r * LDT + half * 16]);
        __syncthreads();

        bf16x8 af[4], b1f[4], b3f[4];
        #pragma unroll
        for (int i = 0; i < 4; i++)
            af[i] = *(const bf16x8*)&As[(wm * 64 + i * 16 + lr) * LDT + lq * 8];
        #pragma unroll
        for (int j = 0; j < 4; j++) {
            b1f[j] = *(const bf16x8*)&B1s[(wn * 64 + j * 16 + lr) * LDT + lq * 8];
            b3f[j] = *(const bf16x8*)&B3s[(wn * 64 + j * 16 + lr) * LDT + lq * 8];
        }
        #pragma unroll
        for (int i = 0; i < 4; i++)
            #pragma unroll
            for (int j = 0; j < 4; j++) {
                acc1[i][j] = __builtin_amdgcn_mfma_f32_16x16x32_bf16(af[i], b1f[j], acc1[i][j], 0, 0, 0);
                acc3[i][j] = __builtin_amdgcn_mfma_f32_16x16x32_bf16(af[i], b3f[j], acc3[i][j], 0, 0, 0);
            }
        __syncthreads();
    }

    // Epilogue: silu(g)*u -> bf16, scatter rows by assignment id.
    // C/D layout: col = lane&15, row(within 16) = (lane>>4)*4 + reg
    #pragma unroll
    for (int i = 0; i < 4; i++) {
        #pragma unroll
        for (int rg = 0; rg < 4; rg++) {
            int mm = mbase + wm * 64 + i * 16 + lq * 4 + rg;
            if (mm >= count) continue;
            int a = lists[e * T_TOK + mm];
            unsigned short* hrow = hgate + (size_t)a * F_DIM + nbase;
            #pragma unroll
            for (int j = 0; j < 4; j++) {
                float g = acc1[i][j][rg];
                float u = acc3[i][j][rg];
                float s = (g / (1.f + __expf(-g))) * u;
                hrow[wn * 64 + j * 16 + lr] = (unsigned short)f2bf(s);
            }
        }
    }
}

// ---------------------------------------------------------------------------
// GEMM2: out[t] += weight * (hgate_row @ w2[e]^T). A = hgate rows (bf16 direct),
// B = w2[e] rows [H,F] (fp32 -> bf16). fp32 atomicAdd scatter into zeroed out.
// ---------------------------------------------------------------------------
__global__ __launch_bounds__(256, 2)
void gemm2_kernel(const unsigned short* __restrict__ hgate,
                  const float* __restrict__ w2,
                  const int* __restrict__ counts,
                  const int* __restrict__ lists,
                  const float* __restrict__ wgt,
                  float* __restrict__ out) {
    const int e = blockIdx.z;
    const int count = counts[e];
    const int mbase = blockIdx.y * BM;
    if (mbase >= count) return;
    const int nbase = blockIdx.x * BN;

    __shared__ short As[BM * LDT];
    __shared__ short Bs[BN * LDT];

    const int tid = threadIdx.x;
    const int r = tid >> 1;
    const int half = tid & 1;

    const unsigned short* arow = nullptr;
    {
        int m = mbase + r;
        if (m < count) {
            int a = lists[e * T_TOK + m];
            arow = hgate + (size_t)a * F_DIM;
        }
    }
    const float* brow = w2 + ((size_t)e * H_DIM + (nbase + r)) * F_DIM;

    const int lane = tid & 63;
    const int wid = tid >> 6;
    const int wm = wid >> 1, wn = wid & 1;
    const int lr = lane & 15, lq = lane >> 4;

    f32x4 acc[4][4];
    #pragma unroll
    for (int i = 0; i < 4; i++)
        #pragma unroll
        for (int j = 0; j < 4; j++) acc[i][j] = (f32x4){0.f, 0.f, 0.f, 0.f};

    for (int k0 = 0; k0 < F_DIM; k0 += BK) {
        const int koff = k0 + half * 16;
        short* adst = &As[r * LDT + half * 16];
        if (arow) {
            const bf16x8* p = (const bf16x8*)(arow + koff);
            *(bf16x8*)adst = p[0];
            *((bf16x8*)adst + 1) = p[1];
        } else {
            zero16_store(adst);
        }
        cvt16_store(brow + koff, &Bs[r * LDT + half * 16]);
        __syncthreads();

        bf16x8 af[4], bf[4];
        #pragma unroll
        for (int i = 0; i < 4; i++)
            af[i] = *(const bf16x8*)&As[(wm * 64 + i * 16 + lr) * LDT + lq * 8];
        #pragma unroll
        for (int j = 0; j < 4; j++)
            bf[j] = *(const bf16x8*)&Bs[(wn * 64 + j * 16 + lr) * LDT + lq * 8];
        #pragma unroll
        for (int i = 0; i < 4; i++)
            #pragma unroll
            for (int j = 0; j < 4; j++)
                acc[i][j] = __builtin_amdgcn_mfma_f32_16x16x32_bf16(af[i], bf[j], acc[i][j], 0, 0, 0);
        __syncthreads();
    }

    #pragma unroll
    for (int i = 0; i < 4; i++) {
        #pragma unroll
        for (int rg = 0; rg < 4; rg++) {
            int mm = mbase + wm * 64 + i * 16 + lq * 4 + rg;
            if (mm >= count) continue;
            int a = lists[e * T_TOK + mm];
            float w = wgt[a];
            int t = a >> 1;
            float* orow = out + (size_t)t * H_DIM + nbase;
            #pragma unroll
            for (int j = 0; j < 4; j++)
                atomicAdd(&orow[wn * 64 + j * 16 + lr], acc[i][j][rg] * w);
        }
    }
}

// ---------------------------------------------------------------------------
extern "C" void kernel_launch(void* const* d_in, const int* in_sizes, int n_in,
                              void* d_out, int out_size, void* d_ws, size_t ws_size,
                              hipStream_t stream) {
    const float* x      = (const float*)d_in[0];  // [T, H]
    const float* gate_w = (const float*)d_in[1];  // [E, H]
    const float* w1     = (const float*)d_in[2];  // [E, F, H]
    const float* w2     = (const float*)d_in[3];  // [E, H, F]
    const float* w3     = (const float*)d_in[4];  // [E, F, H]

    float* out    = (float*)d_out;                      // [T, H]
    float* logits = out + (size_t)T_TOK * H_DIM;        // [T, E]

    // ws layout: counts[8] | lists[E][T] | wgt[2T] | hgate[2T][F] bf16  (~112.3 MiB)
    char* ws = (char*)d_ws;
    int*   counts = (int*)(ws + 0);
    int*   lists  = (int*)(ws + 1024);
    float* wgt    = (float*)(ws + 1024 + (size_t)E_NUM * T_TOK * 4);
    unsigned short* hgate =
        (unsigned short*)(ws + 1024 + (size_t)E_NUM * T_TOK * 4 + (size_t)T_TOK * 2 * 4);

    hipMemsetAsync(counts, 0, E_NUM * sizeof(int), stream);
    hipMemsetAsync(out, 0, (size_t)T_TOK * H_DIM * sizeof(float), stream);

    router_kernel<<<T_TOK / 4, 256, 0, stream>>>(x, gate_w, logits, counts, lists, wgt);

    gemm1_kernel<<<dim3(F_DIM / BN, T_TOK / BM, E_NUM), 256, 0, stream>>>(
        x, w1, w3, counts, lists, hgate);

    gemm2_kernel<<<dim3(H_DIM / BN, T_TOK / BM, E_NUM), 256, 0, stream>>>(
        hgate, w2, counts, lists, wgt, out);
}

// Round 2
// 1227.195 us; speedup vs baseline: 1.1083x; 1.1083x over previous
//
#include <hip/hip_runtime.h>
#include <hip/hip_bf16.h>
#include <stdint.h>

// Problem constants (B=4,S=2048 -> T=8192)
#define T_TOK 8192
#define H_DIM 1024
#define F_DIM 3584
#define E_NUM 8

// GEMM tiling
#define BM 128
#define BN 128
#define BK 32
#define LDT 40   // padded LDS row (bf16 elems): 80B stride -> 16B-aligned b128, phase-balanced banks

typedef __attribute__((ext_vector_type(8))) short bf16x8;
typedef __attribute__((ext_vector_type(4))) float f32x4;

__device__ __forceinline__ short f2bf(float f) {
    union { float f; uint32_t u; } v; v.f = f;
    uint32_t r = v.u + 0x7fffu + ((v.u >> 16) & 1u);   // RNE bf16
    return (short)(r >> 16);
}

// Pack 2 fp32 -> bf16x2 (round-to-nearest, ties away) in ~3 VALU ops via v_perm_b32.
__device__ __forceinline__ uint32_t pack_bf16x2(float a, float b) {
    union { float f; uint32_t u; } ua, ub;
    ua.f = a; ub.f = b;
    return __builtin_amdgcn_perm(ub.u + 0x8000u, ua.u + 0x8000u, 0x07060302u);
}

// 16 fp32 (in regs) -> 16 bf16 -> LDS (two b128 writes).
__device__ __forceinline__ void cvt_store16(const f32x4* v, short* dst) {
    uint32_t w[8];
    #pragma unroll
    for (int i = 0; i < 4; i++) {
        w[2*i]   = pack_bf16x2(v[i][0], v[i][1]);
        w[2*i+1] = pack_bf16x2(v[i][2], v[i][3]);
    }
    ((uint32_t*)dst)[0] = w[0]; ((uint32_t*)dst)[1] = w[1];
    ((uint32_t*)dst)[2] = w[2]; ((uint32_t*)dst)[3] = w[3];
    ((uint32_t*)dst)[4] = w[4]; ((uint32_t*)dst)[5] = w[5];
    ((uint32_t*)dst)[6] = w[6]; ((uint32_t*)dst)[7] = w[7];
}

__device__ __forceinline__ void zero16_store(short* dst) {
    bf16x8 z;
    #pragma unroll
    for (int i = 0; i < 8; i++) z[i] = 0;
    *(bf16x8*)dst = z;
    *((bf16x8*)dst + 1) = z;
}

__device__ __forceinline__ void load16(f32x4* dst, const float* __restrict__ src) {
    const f32x4* p = (const f32x4*)src;
    #pragma unroll
    for (int i = 0; i < 4; i++) dst[i] = p[i];
}

// ---------------------------------------------------------------------------
// Router: one wave per token. fp32 logits (exact), top-2, normalized weights,
// append assignment id a=2t+k to per-expert list.
// ---------------------------------------------------------------------------
__global__ void router_kernel(const float* __restrict__ x,
                              const float* __restrict__ gate_w,
                              float* __restrict__ logits_out,
                              int* __restrict__ counts,
                              int* __restrict__ lists,
                              float* __restrict__ wgt) {
    int wave = (blockIdx.x * blockDim.x + threadIdx.x) >> 6;
    int lane = threadIdx.x & 63;
    if (wave >= T_TOK) return;
    const float* xr = x + (size_t)wave * H_DIM;

    float acc[E_NUM];
    #pragma unroll
    for (int e = 0; e < E_NUM; e++) acc[e] = 0.f;

    for (int i = lane; i < H_DIM; i += 64) {
        float xv = xr[i];
        #pragma unroll
        for (int e = 0; e < E_NUM; e++) acc[e] += xv * gate_w[e * H_DIM + i];
    }
    #pragma unroll
    for (int off = 32; off > 0; off >>= 1) {
        #pragma unroll
        for (int e = 0; e < E_NUM; e++) acc[e] += __shfl_xor(acc[e], off);
    }

    if (lane == 0) {
        int t = wave;
        #pragma unroll
        for (int e = 0; e < E_NUM; e++) logits_out[t * E_NUM + e] = acc[e];
        int i0 = 0; float v0 = acc[0];
        #pragma unroll
        for (int e = 1; e < E_NUM; e++) if (acc[e] > v0) { v0 = acc[e]; i0 = e; }
        int i1 = -1; float v1 = -1e30f;
        #pragma unroll
        for (int e = 0; e < E_NUM; e++) if (e != i0 && acc[e] > v1) { v1 = acc[e]; i1 = e; }
        float e1 = __expf(v1 - v0);
        float inv = 1.f / (1.f + e1);
        int a0 = 2 * t, a1 = 2 * t + 1;
        wgt[a0] = inv;
        wgt[a1] = e1 * inv;
        int p0 = atomicAdd(&counts[i0], 1);
        lists[i0 * T_TOK + p0] = a0;
        int p1 = atomicAdd(&counts[i1], 1);
        lists[i1 * T_TOK + p1] = a1;
    }
}

// ---------------------------------------------------------------------------
// GEMM1: hgate = silu(x @ w1[e]^T) * (x @ w3[e]^T), gathered token rows.
// Register double-buffered: global loads for k+1 issue during MFMA of k.
// ---------------------------------------------------------------------------
__global__ __launch_bounds__(256, 2)
void gemm1_kernel(const float* __restrict__ x,
                  const float* __restrict__ w1,
                  const float* __restrict__ w3,
                  const int* __restrict__ counts,
                  const int* __restrict__ lists,
                  unsigned short* __restrict__ hgate) {
    const int e = blockIdx.z;
    const int count = counts[e];
    const int mbase = blockIdx.y * BM;
    if (mbase >= count) return;
    const int nbase = blockIdx.x * BN;

    __shared__ short As[BM * LDT];
    __shared__ short B1s[BN * LDT];
    __shared__ short B3s[BN * LDT];

    const int tid = threadIdx.x;
    const int r = tid >> 1;      // staging row 0..127
    const int half = tid & 1;    // 16-elem half of the BK=32 K-slice

    const float* arow = nullptr;
    {
        int m = mbase + r;
        if (m < count) {
            int a = lists[e * T_TOK + m];
            arow = x + (size_t)(a >> 1) * H_DIM;
        }
    }
    const float* b1row = w1 + ((size_t)e * F_DIM + (nbase + r)) * H_DIM;
    const float* b3row = w3 + ((size_t)e * F_DIM + (nbase + r)) * H_DIM;

    const int lane = tid & 63;
    const int wid = tid >> 6;
    const int wm = wid >> 1, wn = wid & 1;
    const int lr = lane & 15, lq = lane >> 4;

    f32x4 acc1[4][4], acc3[4][4];
    #pragma unroll
    for (int i = 0; i < 4; i++)
        #pragma unroll
        for (int j = 0; j < 4; j++) {
            acc1[i][j] = (f32x4){0.f, 0.f, 0.f, 0.f};
            acc3[i][j] = (f32x4){0.f, 0.f, 0.f, 0.f};
        }

    // Prefetch k=0 tiles into registers.
    f32x4 ap[4], b1p[4], b3p[4];
    {
        const int koff = half * 16;
        if (arow) load16(ap, arow + koff);
        load16(b1p, b1row + koff);
        load16(b3p, b3row + koff);
    }

    short* adst  = &As[r * LDT + half * 16];
    short* b1dst = &B1s[r * LDT + half * 16];
    short* b3dst = &B3s[r * LDT + half * 16];

    for (int k0 = 0; k0 < H_DIM; k0 += BK) {
        // cvt + store current regs -> LDS
        if (arow) cvt_store16(ap, adst); else zero16_store(adst);
        cvt_store16(b1p, b1dst);
        cvt_store16(b3p, b3dst);
        __syncthreads();

        // issue next K-step's global loads; latency hidden by MFMA phase below
        int kn = k0 + BK;
        if (kn < H_DIM) {
            const int koff = kn + half * 16;
            if (arow) load16(ap, arow + koff);
            load16(b1p, b1row + koff);
            load16(b3p, b3row + koff);
        }

        bf16x8 af[4], b1f[4], b3f[4];
        #pragma unroll
        for (int i = 0; i < 4; i++)
            af[i] = *(const bf16x8*)&As[(wm * 64 + i * 16 + lr) * LDT + lq * 8];
        #pragma unroll
        for (int j = 0; j < 4; j++) {
            b1f[j] = *(const bf16x8*)&B1s[(wn * 64 + j * 16 + lr) * LDT + lq * 8];
            b3f[j] = *(const bf16x8*)&B3s[(wn * 64 + j * 16 + lr) * LDT + lq * 8];
        }
        #pragma unroll
        for (int i = 0; i < 4; i++)
            #pragma unroll
            for (int j = 0; j < 4; j++) {
                acc1[i][j] = __builtin_amdgcn_mfma_f32_16x16x32_bf16(af[i], b1f[j], acc1[i][j], 0, 0, 0);
                acc3[i][j] = __builtin_amdgcn_mfma_f32_16x16x32_bf16(af[i], b3f[j], acc3[i][j], 0, 0, 0);
            }
        __syncthreads();
    }

    // Epilogue: silu(g)*u -> bf16, scatter rows by assignment id.
    // C/D layout: col = lane&15, row(within 16) = (lane>>4)*4 + reg
    #pragma unroll
    for (int i = 0; i < 4; i++) {
        #pragma unroll
        for (int rg = 0; rg < 4; rg++) {
            int mm = mbase + wm * 64 + i * 16 + lq * 4 + rg;
            if (mm >= count) continue;
            int a = lists[e * T_TOK + mm];
            unsigned short* hrow = hgate + (size_t)a * F_DIM + nbase;
            #pragma unroll
            for (int j = 0; j < 4; j++) {
                float g = acc1[i][j][rg];
                float u = acc3[i][j][rg];
                float s = (g / (1.f + __expf(-g))) * u;
                hrow[wn * 64 + j * 16 + lr] = (unsigned short)f2bf(s);
            }
        }
    }
}

// ---------------------------------------------------------------------------
// GEMM2: out[t] += weight * (hgate_row @ w2[e]^T). A = hgate (bf16 direct),
// B = w2 rows fp32->bf16. Register double-buffered. fp32 atomicAdd scatter.
// ---------------------------------------------------------------------------
__global__ __launch_bounds__(256, 2)
void gemm2_kernel(const unsigned short* __restrict__ hgate,
                  const float* __restrict__ w2,
                  const int* __restrict__ counts,
                  const int* __restrict__ lists,
                  const float* __restrict__ wgt,
                  float* __restrict__ out) {
    const int e = blockIdx.z;
    const int count = counts[e];
    const int mbase = blockIdx.y * BM;
    if (mbase >= count) return;
    const int nbase = blockIdx.x * BN;

    __shared__ short As[BM * LDT];
    __shared__ short Bs[BN * LDT];

    const int tid = threadIdx.x;
    const int r = tid >> 1;
    const int half = tid & 1;

    const unsigned short* arow = nullptr;
    {
        int m = mbase + r;
        if (m < count) {
            int a = lists[e * T_TOK + m];
            arow = hgate + (size_t)a * F_DIM;
        }
    }
    const float* brow = w2 + ((size_t)e * H_DIM + (nbase + r)) * F_DIM;

    const int lane = tid & 63;
    const int wid = tid >> 6;
    const int wm = wid >> 1, wn = wid & 1;
    const int lr = lane & 15, lq = lane >> 4;

    f32x4 acc[4][4];
    #pragma unroll
    for (int i = 0; i < 4; i++)
        #pragma unroll
        for (int j = 0; j < 4; j++) acc[i][j] = (f32x4){0.f, 0.f, 0.f, 0.f};

    // Prefetch k=0
    bf16x8 a2p[2];
    f32x4 bp[4];
    {
        const int koff = half * 16;
        if (arow) {
            const bf16x8* p = (const bf16x8*)(arow + koff);
            a2p[0] = p[0]; a2p[1] = p[1];
        }
        load16(bp, brow + koff);
    }

    short* adst = &As[r * LDT + half * 16];
    short* bdst = &Bs[r * LDT + half * 16];

    for (int k0 = 0; k0 < F_DIM; k0 += BK) {
        if (arow) {
            *(bf16x8*)adst = a2p[0];
            *((bf16x8*)adst + 1) = a2p[1];
        } else {
            zero16_store(adst);
        }
        cvt_store16(bp, bdst);
        __syncthreads();

        int kn = k0 + BK;
        if (kn < F_DIM) {
            const int koff = kn + half * 16;
            if (arow) {
                const bf16x8* p = (const bf16x8*)(arow + koff);
                a2p[0] = p[0]; a2p[1] = p[1];
            }
            load16(bp, brow + koff);
        }

        bf16x8 af[4], bf[4];
        #pragma unroll
        for (int i = 0; i < 4; i++)
            af[i] = *(const bf16x8*)&As[(wm * 64 + i * 16 + lr) * LDT + lq * 8];
        #pragma unroll
        for (int j = 0; j < 4; j++)
            bf[j] = *(const bf16x8*)&Bs[(wn * 64 + j * 16 + lr) * LDT + lq * 8];
        #pragma unroll
        for (int i = 0; i < 4; i++)
            #pragma unroll
            for (int j = 0; j < 4; j++)
                acc[i][j] = __builtin_amdgcn_mfma_f32_16x16x32_bf16(af[i], bf[j], acc[i][j], 0, 0, 0);
        __syncthreads();
    }

    #pragma unroll
    for (int i = 0; i < 4; i++) {
        #pragma unroll
        for (int rg = 0; rg < 4; rg++) {
            int mm = mbase + wm * 64 + i * 16 + lq * 4 + rg;
            if (mm >= count) continue;
            int a = lists[e * T_TOK + mm];
            float w = wgt[a];
            int t = a >> 1;
            float* orow = out + (size_t)t * H_DIM + nbase;
            #pragma unroll
            for (int j = 0; j < 4; j++)
                atomicAdd(&orow[wn * 64 + j * 16 + lr], acc[i][j][rg] * w);
        }
    }
}

// ---------------------------------------------------------------------------
extern "C" void kernel_launch(void* const* d_in, const int* in_sizes, int n_in,
                              void* d_out, int out_size, void* d_ws, size_t ws_size,
                              hipStream_t stream) {
    const float* x      = (const float*)d_in[0];  // [T, H]
    const float* gate_w = (const float*)d_in[1];  // [E, H]
    const float* w1     = (const float*)d_in[2];  // [E, F, H]
    const float* w2     = (const float*)d_in[3];  // [E, H, F]
    const float* w3     = (const float*)d_in[4];  // [E, F, H]

    float* out    = (float*)d_out;                      // [T, H]
    float* logits = out + (size_t)T_TOK * H_DIM;        // [T, E]

    // ws layout: counts[8](pad 1KB) | lists[E][T] | wgt[2T] | hgate[2T][F] bf16
    char* ws = (char*)d_ws;
    int*   counts = (int*)(ws + 0);
    int*   lists  = (int*)(ws + 1024);
    float* wgt    = (float*)(ws + 1024 + (size_t)E_NUM * T_TOK * 4);
    unsigned short* hgate =
        (unsigned short*)(ws + 1024 + (size_t)E_NUM * T_TOK * 4 + (size_t)T_TOK * 2 * 4);

    hipMemsetAsync(counts, 0, E_NUM * sizeof(int), stream);
    hipMemsetAsync(out, 0, (size_t)T_TOK * H_DIM * sizeof(float), stream);

    router_kernel<<<T_TOK / 4, 256, 0, stream>>>(x, gate_w, logits, counts, lists, wgt);

    gemm1_kernel<<<dim3(F_DIM / BN, T_TOK / BM, E_NUM), 256, 0, stream>>>(
        x, w1, w3, counts, lists, hgate);

    gemm2_kernel<<<dim3(H_DIM / BN, T_TOK / BM, E_NUM), 256, 0, stream>>>(
        hgate, w2, counts, lists, wgt, out);
}